// Round 15
// baseline (782.731 us; speedup 1.0000x reference)
//
#include <hip/hip_runtime.h>
#include <hip/hip_bf16.h>

// GNN_84043920048593: hetero SAGEConv. f32 I/O.
// R14: 540us; epi_title 104us @ VALUBusy 35%, HBM 15% — exposed A-load
// latency (8 loads then 256 VALU cyc, ~2.6 waves/SIMD). R15: interleave the
// independent operand phases (2 W^T LDS buffers, 2x FMA per sync) + explicit
// kb+4 register prefetch; 4x8 per-thread tile keeps VGPR < 128.

typedef unsigned int u32;
typedef unsigned char u8;

__global__ void sentinel_kernel(float* out, int n) {
    int i = blockIdx.x * 256 + threadIdx.x;
    if (i < n) out[i] = 999.0f;
}

// ---------- CSR build (unchanged from R13) ----------------------------------
__global__ void __launch_bounds__(256)
bin_hist_kernel(const int* __restrict__ dst, int* __restrict__ binhist,
                int n, int shift) {
    __shared__ int lh[256];
    int tid = threadIdx.x;
    lh[tid] = 0;
    __syncthreads();
    int base = blockIdx.x * 4096;
    #pragma unroll
    for (int k = 0; k < 16; ++k) {
        int e = base + k * 256 + tid;
        if (e < n) atomicAdd(&lh[dst[e] >> shift], 1);
    }
    __syncthreads();
    if (lh[tid] > 0) atomicAdd(binhist + tid, lh[tid]);
}

__global__ void __launch_bounds__(256)
bin_scan_kernel(const int* __restrict__ binhist, int* __restrict__ start,
                int* __restrict__ cur_bin, int nbins) {
    __shared__ int sh[256];
    int t = threadIdx.x;
    int v = (t < nbins) ? binhist[t] : 0;
    sh[t] = v;
    __syncthreads();
    for (int off = 1; off < 256; off <<= 1) {
        int u = (t >= off) ? sh[t - off] : 0;
        __syncthreads();
        sh[t] += u;
        __syncthreads();
    }
    if (t < nbins) { start[t] = sh[t] - v; cur_bin[t] = sh[t] - v; }
    if (t == 255) start[nbins] = sh[255];
}

__global__ void __launch_bounds__(256)
bin_scatter_kernel(const int* __restrict__ src, const int* __restrict__ dst,
                   const int* __restrict__ remap,
                   int* __restrict__ cur_bin, u32* __restrict__ staging,
                   int n, int shift) {
    __shared__ int lh[256], sc[256], lrp[256], lcur[256], lbase[256];
    __shared__ u32 stage[4096];
    __shared__ u8  sbin[4096];
    int tid = threadIdx.x;
    lh[tid] = 0;
    __syncthreads();
    int base = blockIdx.x * 4096;
    int mybin[16]; u32 mypk[16];
    int dmask = (1 << shift) - 1;
    #pragma unroll
    for (int k = 0; k < 16; ++k) {
        int e = base + k * 256 + tid;
        mybin[k] = -1;
        if (e < n) {
            int d = dst[e];
            int s = src[e];
            if (remap) s = remap[s];
            int b = d >> shift;
            mybin[k] = b;
            mypk[k] = ((u32)(d & dmask) << 18) | (u32)s;
            atomicAdd(&lh[b], 1);
        }
    }
    __syncthreads();
    int v = lh[tid];
    sc[tid] = v;
    __syncthreads();
    for (int off = 1; off < 256; off <<= 1) {
        int u = (tid >= off) ? sc[tid - off] : 0;
        __syncthreads();
        sc[tid] += u;
        __syncthreads();
    }
    lrp[tid] = sc[tid] - v;
    lcur[tid] = sc[tid] - v;
    if (v > 0) lbase[tid] = atomicAdd(&cur_bin[tid], v);
    __syncthreads();
    #pragma unroll
    for (int k = 0; k < 16; ++k) {
        if (mybin[k] >= 0) {
            int p = atomicAdd(&lcur[mybin[k]], 1);
            stage[p] = mypk[k];
            sbin[p] = (u8)mybin[k];
        }
    }
    __syncthreads();
    int cnt_here = min(4096, n - base);
    for (int i = tid; i < cnt_here; i += 256) {
        int b = sbin[i];
        staging[lbase[b] + (i - lrp[b])] = stage[i];
    }
}

__global__ void __launch_bounds__(256)
bin_build_kernel(const u32* __restrict__ staging, const int* __restrict__ start,
                 int* __restrict__ bucket, int* __restrict__ rp,
                 int* __restrict__ cnt, int shift, int n_dst) {
    __shared__ int fh[1024], frp[1024], fcur[1024], part[256];
    int tid = threadIdx.x;
    int b = blockIdx.x;
    int s0 = start[b], s1 = start[b + 1];
    int m = s1 - s0;
    int nd = 1 << shift;
    int dbase = b << shift;
    for (int j = tid; j < nd; j += 256) fh[j] = 0;
    __syncthreads();
    for (int i = tid; i < m; i += 256)
        atomicAdd(&fh[staging[s0 + i] >> 18], 1);
    __syncthreads();
    int K = nd >> 8;
    int t0 = tid * K;
    int s = 0;
    for (int k = 0; k < K; ++k) s += fh[t0 + k];
    part[tid] = s;
    __syncthreads();
    for (int off = 1; off < 256; off <<= 1) {
        int u = (tid >= off) ? part[tid - off] : 0;
        __syncthreads();
        part[tid] += u;
        __syncthreads();
    }
    int run = part[tid] - s;
    for (int k = 0; k < K; ++k) {
        frp[t0 + k] = run; fcur[t0 + k] = run;
        run += fh[t0 + k];
    }
    __syncthreads();
    for (int j = tid; j < nd; j += 256) {
        int d = dbase + j;
        if (d < n_dst) { rp[d] = s0 + frp[j]; cnt[d] = fh[j]; }
    }
    for (int i = tid; i < m; i += 256) {
        u32 pk = staging[s0 + i];
        int dl = pk >> 18;
        int p = atomicAdd(&fcur[dl], 1);
        bucket[s0 + p] = (int)(pk & 0x3FFFFu);
    }
}

// ---------- gather-reduce (unchanged) ---------------------------------------
__global__ void __launch_bounds__(256)
gather_mean_kernel(const float* __restrict__ x,
                   const int* __restrict__ rp,
                   const int* __restrict__ cnt,
                   const int* __restrict__ bucket,
                   float* __restrict__ agg,
                   int n_dst)
{
    int wave = threadIdx.x >> 6, lane = threadIdx.x & 63;
    int i = blockIdx.x * 4 + wave;
    if (i >= n_dst) return;
    int st = rp[i], deg = cnt[i];
    int q = lane >> 4, c = lane & 15;
    float4 acc = make_float4(0.f, 0.f, 0.f, 0.f);
    for (int j = 0; j < deg; j += 4) {
        int idx = j + q;
        int r = bucket[st + min(idx, deg - 1)];
        float m = (idx < deg) ? 1.0f : 0.0f;
        float4 v = ((const float4*)x)[(size_t)r * 16 + c];
        acc.x += m * v.x; acc.y += m * v.y;
        acc.z += m * v.z; acc.w += m * v.w;
    }
    acc.x += __shfl_xor(acc.x, 16); acc.y += __shfl_xor(acc.y, 16);
    acc.z += __shfl_xor(acc.z, 16); acc.w += __shfl_xor(acc.w, 16);
    acc.x += __shfl_xor(acc.x, 32); acc.y += __shfl_xor(acc.y, 32);
    acc.z += __shfl_xor(acc.z, 32); acc.w += __shfl_xor(acc.w, 32);
    if (q == 0) {
        float inv = 1.0f / fmaxf((float)deg, 1.0f);
        ((float4*)agg)[(size_t)i * 16 + c] =
            make_float4(acc.x * inv, acc.y * inv, acc.z * inv, acc.w * inv);
    }
}

// ---------- epilogues: dual-phase interleave + kb prefetch ------------------
// Block = 128 rows x 64 cols, 256 threads; thread (ty=tid>>3, tx=tid&7) owns
// rows i0..i0+3, cols j0..j0+7. Two W^T matrices in LDS; per kb: prefetch
// next A-regs (both sources), then 256 FMAs (128/iter for single source).

#define LOADW(WB, Wp)                                                       \
    for (int idx = threadIdx.x; idx < 4096; idx += 256) {                   \
        int k = idx >> 6, j = idx & 63;                                     \
        WB[k][j] = (Wp)[j * 64 + k];                                        \
    }
#define LOADW2(WB, Wp, Wq)                                                  \
    for (int idx = threadIdx.x; idx < 4096; idx += 256) {                   \
        int k = idx >> 6, j = idx & 63;                                     \
        WB[k][j] = (Wp)[j * 64 + k] + (Wq)[j * 64 + k];                     \
    }

// dual-source interleaved pass: acc[r][0..7] += A[rr]·W0^T + X[rr]·W1^T
#define DUAL_PASS(SRCA, SRCX, W0, W1)                                       \
    {                                                                       \
        float4 cA[4], cX[4], nA[4], nX[4];                                  \
        _Pragma("unroll")                                                   \
        for (int r = 0; r < 4; ++r) {                                       \
            cA[r] = *(const float4*)((SRCA(r)));                            \
            cX[r] = *(const float4*)((SRCX(r)));                            \
        }                                                                   \
        for (int kb = 0; kb < 64; kb += 4) {                                \
            if (kb < 60) {                                                  \
                _Pragma("unroll")                                           \
                for (int r = 0; r < 4; ++r) {                               \
                    nA[r] = *(const float4*)((SRCA(r)) + kb + 4);           \
                    nX[r] = *(const float4*)((SRCX(r)) + kb + 4);           \
                }                                                           \
            }                                                               \
            _Pragma("unroll")                                               \
            for (int kk = 0; kk < 4; ++kk) {                                \
                float4 wa0 = *(const float4*)(&W0[kb + kk][j0]);            \
                float4 wa1 = *(const float4*)(&W0[kb + kk][j0 + 4]);        \
                float4 wb0 = *(const float4*)(&W1[kb + kk][j0]);            \
                float4 wb1 = *(const float4*)(&W1[kb + kk][j0 + 4]);        \
                _Pragma("unroll")                                           \
                for (int r = 0; r < 4; ++r) {                               \
                    float avA = ((const float*)&cA[r])[kk];                 \
                    float avX = ((const float*)&cX[r])[kk];                 \
                    acc[r][0] += avA * wa0.x; acc[r][1] += avA * wa0.y;     \
                    acc[r][2] += avA * wa0.z; acc[r][3] += avA * wa0.w;     \
                    acc[r][4] += avA * wa1.x; acc[r][5] += avA * wa1.y;     \
                    acc[r][6] += avA * wa1.z; acc[r][7] += avA * wa1.w;     \
                    acc[r][0] += avX * wb0.x; acc[r][1] += avX * wb0.y;     \
                    acc[r][2] += avX * wb0.z; acc[r][3] += avX * wb0.w;     \
                    acc[r][4] += avX * wb1.x; acc[r][5] += avX * wb1.y;     \
                    acc[r][6] += avX * wb1.z; acc[r][7] += avX * wb1.w;     \
                }                                                           \
            }                                                               \
            _Pragma("unroll")                                               \
            for (int r = 0; r < 4; ++r) { cA[r] = nA[r]; cX[r] = nX[r]; }   \
        }                                                                   \
    }

// single-source pass with prefetch
#define SINGLE_PASS(SRCA, W0)                                               \
    {                                                                       \
        float4 cA[4], nA[4];                                                \
        _Pragma("unroll")                                                   \
        for (int r = 0; r < 4; ++r) cA[r] = *(const float4*)((SRCA(r)));    \
        for (int kb = 0; kb < 64; kb += 4) {                                \
            if (kb < 60) {                                                  \
                _Pragma("unroll")                                           \
                for (int r = 0; r < 4; ++r)                                 \
                    nA[r] = *(const float4*)((SRCA(r)) + kb + 4);           \
            }                                                               \
            _Pragma("unroll")                                               \
            for (int kk = 0; kk < 4; ++kk) {                                \
                float4 wa0 = *(const float4*)(&W0[kb + kk][j0]);            \
                float4 wa1 = *(const float4*)(&W0[kb + kk][j0 + 4]);        \
                _Pragma("unroll")                                           \
                for (int r = 0; r < 4; ++r) {                               \
                    float avA = ((const float*)&cA[r])[kk];                 \
                    acc[r][0] += avA * wa0.x; acc[r][1] += avA * wa0.y;     \
                    acc[r][2] += avA * wa0.z; acc[r][3] += avA * wa0.w;     \
                    acc[r][4] += avA * wa1.x; acc[r][5] += avA * wa1.y;     \
                    acc[r][6] += avA * wa1.z; acc[r][7] += avA * wa1.w;     \
                }                                                           \
            }                                                               \
            _Pragma("unroll")                                               \
            for (int r = 0; r < 4; ++r) cA[r] = nA[r];                      \
        }                                                                   \
    }

__global__ void __launch_bounds__(256, 4)
epi_label_kernel(const float* __restrict__ agg_tl,
                 const float* __restrict__ agg_ll,
                 const float* __restrict__ xemb,
                 const int* __restrict__ nid,
                 const float* __restrict__ Wl_tl, const float* __restrict__ bl_tl,
                 const float* __restrict__ Wr_tl,
                 const float* __restrict__ Wl_ll, const float* __restrict__ bl_ll,
                 const float* __restrict__ Wr_ll,
                 float* __restrict__ out, int n)
{
    __shared__ float w0[64][64];
    __shared__ float w1[64][64];

    int ty = threadIdx.x >> 3, tx = threadIdx.x & 7;   // 32 x 8
    int i0 = blockIdx.x * 128 + ty * 4;
    int j0 = tx * 8;

    int rr[4], nd[4];
    #pragma unroll
    for (int r = 0; r < 4; ++r) rr[r] = min(i0 + r, n - 1);
    #pragma unroll
    for (int r = 0; r < 4; ++r) nd[r] = nid[rr[r]];

    float acc[4][8];
    #pragma unroll
    for (int r = 0; r < 4; ++r)
        #pragma unroll
        for (int c = 0; c < 8; ++c)
            acc[r][c] = bl_tl[j0 + c] + bl_ll[j0 + c];

    // pass 1: agg_tl x Wl_tl^T  interleaved with  agg_ll x Wl_ll^T
    LOADW(w0, Wl_tl)
    LOADW(w1, Wl_ll)
    __syncthreads();
    #define SA(r) (agg_tl + (size_t)rr[r] * 64)
    #define SX(r) (agg_ll + (size_t)rr[r] * 64)
    DUAL_PASS(SA, SX, w0, w1)
    #undef SA
    #undef SX
    __syncthreads();

    // pass 2: x_label x (Wr_tl + Wr_ll)^T
    LOADW2(w0, Wr_tl, Wr_ll)
    __syncthreads();
    #define SA(r) (xemb + (size_t)nd[r] * 64)
    SINGLE_PASS(SA, w0)
    #undef SA

    #pragma unroll
    for (int r = 0; r < 4; ++r) {
        if (i0 + r < n) {
            float4 o0, o1;
            o0.x = fmaxf(acc[r][0], 0.0f); o0.y = fmaxf(acc[r][1], 0.0f);
            o0.z = fmaxf(acc[r][2], 0.0f); o0.w = fmaxf(acc[r][3], 0.0f);
            o1.x = fmaxf(acc[r][4], 0.0f); o1.y = fmaxf(acc[r][5], 0.0f);
            o1.z = fmaxf(acc[r][6], 0.0f); o1.w = fmaxf(acc[r][7], 0.0f);
            *(float4*)(out + (size_t)(i0 + r) * 64 + j0)     = o0;
            *(float4*)(out + (size_t)(i0 + r) * 64 + j0 + 4) = o1;
        }
    }
}

__global__ void __launch_bounds__(256, 4)
epi_title_kernel(const float* __restrict__ agg_lt,
                 const float* __restrict__ title_x,
                 const float* __restrict__ Wl_tl, const float* __restrict__ bl_tl,
                 const float* __restrict__ Wr_tl,
                 float* __restrict__ out, int n)
{
    __shared__ float w0[64][64];
    __shared__ float w1[64][64];

    int ty = threadIdx.x >> 3, tx = threadIdx.x & 7;
    int i0 = blockIdx.x * 128 + ty * 4;
    int j0 = tx * 8;

    int rr[4];
    #pragma unroll
    for (int r = 0; r < 4; ++r) rr[r] = min(i0 + r, n - 1);

    float acc[4][8];
    #pragma unroll
    for (int r = 0; r < 4; ++r)
        #pragma unroll
        for (int c = 0; c < 8; ++c)
            acc[r][c] = bl_tl[j0 + c];

    LOADW(w0, Wl_tl)
    LOADW(w1, Wr_tl)
    __syncthreads();
    #define SA(r) (agg_lt  + (size_t)rr[r] * 64)
    #define SX(r) (title_x + (size_t)rr[r] * 64)
    DUAL_PASS(SA, SX, w0, w1)
    #undef SA
    #undef SX

    #pragma unroll
    for (int r = 0; r < 4; ++r) {
        if (i0 + r < n) {
            float4 o0, o1;
            o0.x = fmaxf(acc[r][0], 0.0f); o0.y = fmaxf(acc[r][1], 0.0f);
            o0.z = fmaxf(acc[r][2], 0.0f); o0.w = fmaxf(acc[r][3], 0.0f);
            o1.x = fmaxf(acc[r][4], 0.0f); o1.y = fmaxf(acc[r][5], 0.0f);
            o1.z = fmaxf(acc[r][6], 0.0f); o1.w = fmaxf(acc[r][7], 0.0f);
            *(float4*)(out + (size_t)(i0 + r) * 64 + j0)     = o0;
            *(float4*)(out + (size_t)(i0 + r) * 64 + j0 + 4) = o1;
        }
    }
}

extern "C" void kernel_launch(void* const* d_in, const int* in_sizes, int n_in,
                              void* d_out, int out_size, void* d_ws, size_t ws_size,
                              hipStream_t stream)
{
    const float* title_x   = (const float*)d_in[0];
    const float* label_emb = (const float*)d_in[1];
    const float* Wl_tl     = (const float*)d_in[2];
    const float* bl_tl     = (const float*)d_in[3];
    const float* Wr_tl     = (const float*)d_in[4];
    const float* Wl_ll     = (const float*)d_in[5];
    const float* bl_ll     = (const float*)d_in[6];
    const float* Wr_ll     = (const float*)d_in[7];
    const int* label_node_id = (const int*)d_in[8];
    const int* tl_src = (const int*)d_in[9];
    const int* tl_dst = (const int*)d_in[10];
    const int* lt_src = (const int*)d_in[11];
    const int* lt_dst = (const int*)d_in[12];
    const int* ll_src = (const int*)d_in[13];
    const int* ll_dst = (const int*)d_in[14];

    const int NT  = in_sizes[0] / 64;
    const int NL  = in_sizes[8];
    const int eTL = in_sizes[9];
    const int eLT = in_sizes[11];
    const int eLL = in_sizes[13];

    const int SH_L = 9,  NB_L = (NL + 511) >> 9;
    const int SH_T = 10, NB_T = (NT + 1023) >> 10;

    size_t szAgL = (size_t)NL * 64 * 4;
    size_t szAgT = (size_t)NT * 64 * 4;
    size_t iNL   = (size_t)NL * 4;
    size_t iNT   = (size_t)NT * 4;

    size_t regionA = 2 * szAgL + 4 * iNL + ((size_t)eTL + eLL) * 4;
    size_t regionB = szAgT + 2 * iNT + (size_t)eLT * 4;
    size_t big     = regionA > regionB ? regionA : regionB;
    size_t szSmall = (256 + 257 + 256) * 4;
    size_t needed  = big + szSmall;

    float* out_label = (float*)d_out;
    float* out_title = out_label + (size_t)NL * 64;

    if (ws_size < needed) {
        sentinel_kernel<<<(out_size + 255) / 256, 256, 0, stream>>>((float*)d_out, out_size);
        return;
    }

    char* base = (char*)d_ws;
    float* agg_tl  = (float*)(base);
    float* agg_ll  = (float*)(base + szAgL);
    u32*   stagA   = (u32*)  (base + szAgL);
    int* rp_tl  = (int*)(base + 2 * szAgL);
    int* cnt_tl = (int*)(base + 2 * szAgL + iNL);
    int* rp_ll  = (int*)(base + 2 * szAgL + 2 * iNL);
    int* cnt_ll = (int*)(base + 2 * szAgL + 3 * iNL);
    int* bkt_tl = (int*)(base + 2 * szAgL + 4 * iNL);
    int* bkt_ll = bkt_tl + eTL;
    float* agg_lt = (float*)(base);
    u32*   stagB  = (u32*)(base);
    int* rp_lt  = (int*)(base + szAgT);
    int* cnt_lt = (int*)(base + szAgT + iNT);
    int* bkt_lt = (int*)(base + szAgT + 2 * iNT);
    int* binhist = (int*)(base + big);
    int* startb  = binhist + 256;
    int* curbin  = startb + 257;

    auto nchunk = [](int n) { return (n + 4095) / 4096; };

    auto build_csr = [&](const int* esrc, const int* edst, const int* remap,
                         u32* staging, int* bucket, int* rp, int* cnt,
                         int n_edges, int n_dst, int shift, int nbins) {
        (void)hipMemsetAsync(binhist, 0, nbins * 4, stream);
        bin_hist_kernel<<<nchunk(n_edges), 256, 0, stream>>>(edst, binhist, n_edges, shift);
        bin_scan_kernel<<<1, 256, 0, stream>>>(binhist, startb, curbin, nbins);
        bin_scatter_kernel<<<nchunk(n_edges), 256, 0, stream>>>(
            esrc, edst, remap, curbin, staging, n_edges, shift);
        bin_build_kernel<<<nbins, 256, 0, stream>>>(
            staging, startb, bucket, rp, cnt, shift, n_dst);
    };

    // ---- phase A: label destination ----------------------------------------
    build_csr(tl_src, tl_dst, nullptr,       stagA, bkt_tl, rp_tl, cnt_tl, eTL, NL, SH_L, NB_L);
    build_csr(ll_src, ll_dst, label_node_id, stagA, bkt_ll, rp_ll, cnt_ll, eLL, NL, SH_L, NB_L);
    gather_mean_kernel<<<(NL + 3) / 4, 256, 0, stream>>>(title_x,   rp_tl, cnt_tl, bkt_tl, agg_tl, NL);
    gather_mean_kernel<<<(NL + 3) / 4, 256, 0, stream>>>(label_emb, rp_ll, cnt_ll, bkt_ll, agg_ll, NL);
    epi_label_kernel<<<(NL + 127) / 128, 256, 0, stream>>>(
        agg_tl, agg_ll, label_emb, label_node_id,
        Wl_tl, bl_tl, Wr_tl, Wl_ll, bl_ll, Wr_ll, out_label, NL);

    // ---- phase B: title destination (stream-ordered reuse) -----------------
    build_csr(lt_src, lt_dst, label_node_id, stagB, bkt_lt, rp_lt, cnt_lt, eLT, NT, SH_T, NB_T);
    gather_mean_kernel<<<(NT + 3) / 4, 256, 0, stream>>>(label_emb, rp_lt, cnt_lt, bkt_lt, agg_lt, NT);
    epi_title_kernel<<<(NT + 127) / 128, 256, 0, stream>>>(
        agg_lt, title_x, Wl_tl, bl_tl, Wr_tl, out_title, NT);
}